// Round 2
// baseline (452.745 us; speedup 1.0000x reference)
//
#include <hip/hip_runtime.h>
#include <stdint.h>
#include <math.h>

// Problem constants (from reference):
#define BB 8
#define CC 32
#define TT 3136      // 56*56
#define KK 9
#define OC 64

// ---------------------------------------------------------------------------
// Kernel 1: transposed copy + fp64 inverse norms.
//   xfT[b][t][c]  = x[b][c][t]                       (fp32)
//   invn[b][t]    = 1/max(sqrt(sum_c x^2), 1e-12)    (fp64, exact-ish)
// ---------------------------------------------------------------------------
__global__ __launch_bounds__(256) void norm_kernel(
    const float* __restrict__ x, float* __restrict__ xfT, double* __restrict__ invn)
{
    int t = blockIdx.x * 256 + threadIdx.x;
    int b = blockIdx.y;
    if (t >= TT) return;
    const float* xp = x + (size_t)b * CC * TT + t;
    float v[CC];
    double ss = 0.0;
#pragma unroll
    for (int c = 0; c < CC; ++c) {
        v[c] = xp[(size_t)c * TT];
        ss = fma((double)v[c], (double)v[c], ss);
    }
    invn[(size_t)b * TT + t] = 1.0 / fmax(sqrt(ss), 1e-12);
    float* pf = xfT + ((size_t)b * TT + t) * CC;
#pragma unroll
    for (int c = 0; c < CC; c += 4)
        *(float4*)(pf + c) = make_float4(v[c], v[c+1], v[c+2], v[c+3]);
}

// ---------------------------------------------------------------------------
// Kernel 2: fused sim row + top-8-of-others (self always included).
// Ranking score (fp64): dot(x_t, x_s) * invn[s]  — same ordering as cosine
// sim for fixed t (invn[t] > 0 is a constant factor; clip can't reorder).
// Block: 256 threads = 32 rows x 8 column-interleaved scanners.
// Column tile (64 cols) staged in LDS as fp64, stride 34 doubles:
// 8 distinct b128 addresses/wave -> disjoint 4-bank spans, conflict-free.
// ---------------------------------------------------------------------------
#define STILE 64
#define RPB   32

__global__ __launch_bounds__(256) void topk_kernel(
    const float* __restrict__ xfT, const double* __restrict__ invn,
    int* __restrict__ idxo)
{
    __shared__ double cols[STILE * 34];   // [col][0..31]=values, [32]=invn
    __shared__ double mval[256 * 8];
    __shared__ int    midx[256 * 8];

    int tid = threadIdx.x;
    int b   = blockIdx.y;
    int r   = tid >> 3;          // row within block   (0..31)
    int q   = tid & 7;           // scanner within row (0..7)
    int t   = blockIdx.x * RPB + r;

    // row vector in fp64 registers
    const float* rowp = xfT + ((size_t)b * TT + t) * CC;
    double rv[CC];
#pragma unroll
    for (int c = 0; c < CC; c += 4) {
        float4 f = *(const float4*)(rowp + c);
        rv[c] = (double)f.x; rv[c+1] = (double)f.y;
        rv[c+2] = (double)f.z; rv[c+3] = (double)f.w;
    }

    double val[8];
    int    ids[8];
#pragma unroll
    for (int j = 0; j < 8; ++j) { val[j] = -1.0e300; ids[j] = 0x7FFFFFFF; }

    // staging role: 4 threads per column, 8 floats each
    int scol = tid >> 2;         // 0..63
    int part = tid & 3;          // 0..3

    for (int s0 = 0; s0 < TT; s0 += STILE) {
        __syncthreads();
        const float* gp = xfT + ((size_t)b * TT + (s0 + scol)) * CC + part * 8;
        float4 a0 = *(const float4*)(gp);
        float4 a1 = *(const float4*)(gp + 4);
        double* cd = &cols[scol * 34 + part * 8];
        cd[0] = (double)a0.x; cd[1] = (double)a0.y;
        cd[2] = (double)a0.z; cd[3] = (double)a0.w;
        cd[4] = (double)a1.x; cd[5] = (double)a1.y;
        cd[6] = (double)a1.z; cd[7] = (double)a1.w;
        if (part == 3) cols[scol * 34 + 32] = invn[(size_t)b * TT + (s0 + scol)];
        __syncthreads();

#pragma unroll
        for (int i = 0; i < STILE / 8; ++i) {
            int sl = i * 8 + q;
            int s  = s0 + sl;
            const double* cb = &cols[sl * 34];
            double acc = 0.0;
#pragma unroll
            for (int c = 0; c < CC; c += 2) {
                double2 cv = *(const double2*)(cb + c);
                acc = fma(rv[c],   cv.x, acc);
                acc = fma(rv[c+1], cv.y, acc);
            }
            double scr = acc * cb[32];
            if (s == t) continue;                 // self handled separately
            if (scr > val[7]) {
                val[7] = scr; ids[7] = s;
#pragma unroll
                for (int j = 7; j > 0; --j) {
                    if (val[j] > val[j-1]) {
                        double tv = val[j]; val[j] = val[j-1]; val[j-1] = tv;
                        int    ti = ids[j]; ids[j] = ids[j-1]; ids[j-1] = ti;
                    }
                }
            }
        }
    }

#pragma unroll
    for (int j = 0; j < 8; ++j) { mval[tid * 8 + j] = val[j]; midx[tid * 8 + j] = ids[j]; }
    __syncthreads();

    if (q == 0) {
        // merge 8 sorted lists -> top-8 (value desc, index asc on ties)
        int p[8] = {0,0,0,0,0,0,0,0};
        int oi[9];
#pragma unroll
        for (int m = 0; m < 8; ++m) {
            double best = -1.0e301; int bi = 0x7FFFFFFF; int bq = 0;
#pragma unroll
            for (int qq = 0; qq < 8; ++qq) {
                if (p[qq] < 8) {
                    int base = (r * 8 + qq) * 8 + p[qq];
                    double v = mval[base]; int id = midx[base];
                    if (v > best || (v == best && id < bi)) { best = v; bi = id; bq = qq; }
                }
            }
            ++p[bq];
            oi[m] = bi;
        }
        oi[8] = t;   // self (sim forced to 1.1 -> always top-1)
        // insertion sort ascending
        for (int a = 1; a < 9; ++a) {
            int kv = oi[a]; int jj = a - 1;
            while (jj >= 0 && oi[jj] > kv) { oi[jj+1] = oi[jj]; --jj; }
            oi[jj+1] = kv;
        }
        int* op = idxo + ((size_t)b * TT + t) * KK;
#pragma unroll
        for (int m = 0; m < 9; ++m) op[m] = oi[m];
    }
}

// ---------------------------------------------------------------------------
// Kernel 3: gather + conv1d(kernel=K, stride=K).
//   out[b][o][t] = sum_{k,c} W[o][c][k] * xfT[b][idx[b][t][k]][c]
// ---------------------------------------------------------------------------
__global__ __launch_bounds__(256) void gconv_kernel(
    const float* __restrict__ xfT, const int* __restrict__ idxi,
    const float* __restrict__ Wt, float* __restrict__ out)
{
    __shared__ float wl[288 * 65];
    __shared__ float ot[4][64 * 17];

    int tid = threadIdx.x;
    int b   = blockIdx.y;
    int t0  = blockIdx.x * 64;

    // stage W: global [o][c][k] (o*288 + ck) -> wl[ck*65 + o]
    for (int f = tid; f < OC * 288; f += 256) {
        int o  = f / 288;
        int ck = f - o * 288;
        wl[ck * 65 + o] = Wt[f];
    }
    __syncthreads();

    int w    = tid >> 6;
    int lane = tid & 63;        // = output channel o
    int tw0  = t0 + w * 16;

    for (int i = 0; i < 16; ++i) {
        int t = tw0 + i;
        const int* ip = idxi + ((size_t)b * TT + t) * KK;
        float acc = 0.f;
#pragma unroll
        for (int k = 0; k < KK; ++k) {
            int s = __builtin_amdgcn_readfirstlane(ip[k]);
            const float* col = xfT + ((size_t)b * TT + s) * CC;
#pragma unroll
            for (int c4 = 0; c4 < CC; c4 += 4) {
                float4 xv = *(const float4*)(col + c4);
                acc = fmaf(xv.x, wl[((c4+0)*9 + k)*65 + lane], acc);
                acc = fmaf(xv.y, wl[((c4+1)*9 + k)*65 + lane], acc);
                acc = fmaf(xv.z, wl[((c4+2)*9 + k)*65 + lane], acc);
                acc = fmaf(xv.w, wl[((c4+3)*9 + k)*65 + lane], acc);
            }
        }
        ot[w][lane * 17 + i] = acc;
    }
    __syncthreads();

    for (int j = 0; j < 16; ++j) {
        int fl = j * 64 + lane;
        int o  = fl >> 4;
        int ii = fl & 15;
        out[((size_t)b * OC + o) * TT + tw0 + ii] = ot[w][o * 17 + ii];
    }
}

// ---------------------------------------------------------------------------
extern "C" void kernel_launch(void* const* d_in, const int* in_sizes, int n_in,
                              void* d_out, int out_size, void* d_ws, size_t ws_size,
                              hipStream_t stream)
{
    const float* x  = (const float*)d_in[0];   // [8][32][56][56]
    const float* Wt = (const float*)d_in[1];   // [64][32][9]
    float* out = (float*)d_out;                // [8][64][56][56]

    // workspace layout: xfT (fp32) | invn (fp64) | idx (int)
    float*  xfT  = (float*)d_ws;
    double* invn = (double*)(xfT + (size_t)BB * TT * CC);           // 3.2MB offset, 8B-aligned
    int*    idw  = (int*)(invn + (size_t)BB * TT);

    dim3 g1((TT + 255) / 256, BB);
    norm_kernel<<<g1, 256, 0, stream>>>(x, xfT, invn);

    dim3 g2(TT / RPB, BB);   // 98 x 8 = 784 blocks
    topk_kernel<<<g2, 256, 0, stream>>>(xfT, invn, idw);

    dim3 g3(TT / 64, BB);    // 49 x 8 = 392 blocks
    gconv_kernel<<<g3, 256, 0, stream>>>(xfT, idw, Wt, out);
}